// Round 3
// baseline (286.954 us; speedup 1.0000x reference)
//
#include <hip/hip_runtime.h>
#include <hip/hip_bf16.h>
#include <stdint.h>

// Problem constants (B=8192, I=512, H=1024, D=8)
#define B_N 8192
#define I_N 512
#define H_N 1024

typedef __bf16 bf16x8 __attribute__((ext_vector_type(8)));
typedef float f32x4 __attribute__((ext_vector_type(4)));
typedef unsigned short u16;
typedef unsigned int u32;

__device__ inline void gld_lds16(const void* g, void* l) {
  __builtin_amdgcn_global_load_lds(
      (const __attribute__((address_space(1))) unsigned int*)g,
      (__attribute__((address_space(3))) unsigned int*)l,
      16, 0, 0);
}

__device__ inline u16 f2bf(float f) {
  __hip_bfloat16 h = __float2bfloat16(f);
  return __builtin_bit_cast(u16, h);
}

__device__ inline float bf2f(u16 b) {
  unsigned int u = ((unsigned int)b) << 16;
  return __builtin_bit_cast(float, u);
}

__device__ inline u32 pack2bf(float lo, float hi) {
  return (u32)f2bf(lo) | ((u32)f2bf(hi) << 16);
}

// ---------------- prep: fused bf16 conversion (x, Wih, Whh) + hidden decay ----
// cvt part: blocks [0, 4352) — 8 f32 -> 8 bf16 per thread, coalesced.
// decay part: blocks [4352, 8448) — 8 elements per thread:
// hdec = exp(-relu(delta @ Wg^T + bg)) * h, bf16x8 store.
__global__ void prep(const float* __restrict__ x, const float* __restrict__ wih,
                     const float* __restrict__ whh, const float* __restrict__ h,
                     const float* __restrict__ delta, const float* __restrict__ wg,
                     const float* __restrict__ bg, u16* __restrict__ xb,
                     u16* __restrict__ wihb, u16* __restrict__ whhb,
                     u16* __restrict__ hdec) {
  const int b = blockIdx.x;
  if (b < 4352) {
    const float* src; u16* dst; int base;
    if (b < 2048)      { src = x;   dst = xb;   base = b; }
    else if (b < 2816) { src = wih; dst = wihb; base = b - 2048; }
    else               { src = whh; dst = whhb; base = b - 2816; }
    const int i = (base * 256 + (int)threadIdx.x) * 8;
    float4 a0 = *(const float4*)(src + i);
    float4 a1 = *(const float4*)(src + i + 4);
    union { u16 u[8]; float4 v; } pk;
    pk.u[0] = f2bf(a0.x); pk.u[1] = f2bf(a0.y); pk.u[2] = f2bf(a0.z); pk.u[3] = f2bf(a0.w);
    pk.u[4] = f2bf(a1.x); pk.u[5] = f2bf(a1.y); pk.u[6] = f2bf(a1.z); pk.u[7] = f2bf(a1.w);
    *(float4*)(dst + i) = pk.v;
  } else {
    const int idx8 = (b - 4352) * 2048 + (int)threadIdx.x * 8;  // over B*H, 8-aligned
    const int bb = idx8 >> 10;   // H_N = 1024
    const int j  = idx8 & 1023;
    const float4* d4 = (const float4*)(delta + (size_t)bb * 8);
    const float4 d0 = d4[0], d1 = d4[1];
    const float4* h4 = (const float4*)(h + idx8);
    const float4 h0 = h4[0], h1 = h4[1];
    const float4* b4 = (const float4*)(bg + j);
    const float4 bg0 = b4[0], bg1 = b4[1];
    const float hv[8]  = {h0.x, h0.y, h0.z, h0.w, h1.x, h1.y, h1.z, h1.w};
    const float bgv[8] = {bg0.x, bg0.y, bg0.z, bg0.w, bg1.x, bg1.y, bg1.z, bg1.w};
    union { u16 u[8]; float4 v; } pk;
#pragma unroll
    for (int t = 0; t < 8; ++t) {
      const float4* w4 = (const float4*)(wg + (size_t)(j + t) * 8);
      const float4 w0 = w4[0], w1 = w4[1];
      float s = d0.x*w0.x + d0.y*w0.y + d0.z*w0.z + d0.w*w0.w
              + d1.x*w1.x + d1.y*w1.y + d1.z*w1.z + d1.w*w1.w + bgv[t];
      s = s > 0.0f ? s : 0.0f;
      pk.u[t] = f2bf(__expf(-s) * hv[t]);
    }
    *(float4*)(hdec + idx8) = pk.v;
  }
}

// ---------- fused GRU GEMM — 8-wave, 4-sub-phase interleaved schedule ----------
// Port of the verified m201 8-phase template shape to the fused 3-gate GEMM.
// Block: 512 threads (8 waves), tile BM=256 rows x BN=64 cols x 3 gates, BK=64.
// Waves: wm = wave&3 (64-row quarter), wn = wave>>2 (32-col half).
// Wave tile 64x32x3 gates (acc layout IDENTICAL to prior version).
// LDS: double-buffered As[2][2][256*32] (64 KB) + Ws[2][3][2][64*32] (48 KB)
//      = 112 KB -> 1 block/CU, 2 waves/SIMD (m201 ran the same occupancy).
// Per K-tile (64): 4 phases, each {ds_read subtile -> s_barrier -> lgkmcnt(0)
//   -> setprio(1) 12xMFMA setprio(0) -> s_barrier}. All 7 global_load_lds for
// tile t+1 issue in phase 0 of tile t (~3.5 phases of latency cover); single
// vmcnt(0) just before the tile's final barrier (loads are ~400 cy old there).
// XOR chunk swizzle identical to verified-conflict-free prior version.
// MFMA accumulation order over K identical to prior version -> same absmax.

#define BAR do { asm volatile("" ::: "memory"); __builtin_amdgcn_s_barrier(); \
                 asm volatile("" ::: "memory"); } while (0)
#define WAITVM0 asm volatile("s_waitcnt vmcnt(0)" ::: "memory")
#define LGKM0   asm volatile("s_waitcnt lgkmcnt(0)" ::: "memory")

__global__ __launch_bounds__(512, 2) void gru_gemm(
    const u16* __restrict__ xb,    // [B, I] bf16
    const u16* __restrict__ hdec,  // [B, H] bf16 (decayed h)
    const u16* __restrict__ wihb,  // [3H, I] bf16
    const u16* __restrict__ whhb,  // [3H, H] bf16
    const float* __restrict__ bih, // [3H]
    const float* __restrict__ bhh, // [3H]
    float* __restrict__ out)       // [B, H] f32
{
  __shared__ __attribute__((aligned(16))) u16 As[2][2][256 * 32];   // 64 KB
  __shared__ __attribute__((aligned(16))) u16 Ws[2][3][2][64 * 32]; // 48 KB

  const int tid  = threadIdx.x;
  const int lane = tid & 63;
  const int wave = tid >> 6;
  const int wm = wave & 3;    // row quarter (64 rows each)
  const int wn = wave >> 2;   // col half (32 cols each)
  const int m0 = blockIdx.x * 256;
  const int j0 = blockIdx.y * 64;

  // staging addressing (512 threads)
  const int srow = tid >> 2;                                // 0..127 A staging row
  const int sk   = (((tid & 3) ^ ((tid >> 3) & 3)) * 8);    // swizzled global chunk
  const int wrow = (tid >> 2) & 63;                         // W staging row
  const int wkb  = tid >> 8;                                // W staging kb half
  // fragment addressing (per lane)
  const int frow = lane & 15;                               // fragment row/col
  const int fkp  = (((lane >> 4) ^ ((frow >> 1) & 3)) * 8); // swizzled read offset

  f32x4 acc[3][4][2];
  u32 park[3][4][2][2];
  bf16x8 af[4];
  bf16x8 wf[3];

#pragma unroll
  for (int g = 0; g < 3; ++g)
#pragma unroll
    for (int rb = 0; rb < 4; ++rb)
#pragma unroll
      for (int cb = 0; cb < 2; ++cb)
#pragma unroll
        for (int r = 0; r < 4; ++r) acc[g][rb][cb][r] = 0.0f;

// 7 loads per K-tile: 4 A (2 kb x 2 row-halves of 128) + 3 W (one per gate,
// each 16B/thread covering both kb halves: kb = tid>>8).
#define STAGE_TILE(APTR, WPTR, LD, bb, kk)                                       \
  do {                                                                           \
    _Pragma("unroll")                                                            \
    for (int l = 0; l < 4; ++l) {                                                \
      const int kb = l & 1, ro = (l >> 1) * 128;                                 \
      gld_lds16((APTR) + (size_t)(m0 + ro + srow) * (LD) + (kk) + kb * 32 + sk,  \
                &As[bb][kb][ro * 32 + tid * 8]);                                 \
    }                                                                            \
    _Pragma("unroll")                                                            \
    for (int g = 0; g < 3; ++g)                                                  \
      gld_lds16((WPTR) + (size_t)(g * H_N + j0 + wrow) * (LD) + (kk) + wkb * 32 + sk, \
                &Ws[bb][g][0][tid * 8]);                                         \
  } while (0)

#define READ_AF(bb, kb)                                                          \
  do {                                                                           \
    _Pragma("unroll")                                                            \
    for (int rb = 0; rb < 4; ++rb)                                               \
      af[rb] = *(const bf16x8*)&As[bb][kb][(wm * 64 + rb * 16 + frow) * 32 + fkp]; \
  } while (0)

#define READ_WF(bb, kb, cb)                                                      \
  do {                                                                           \
    _Pragma("unroll")                                                            \
    for (int g = 0; g < 3; ++g)                                                  \
      wf[g] = *(const bf16x8*)&Ws[bb][g][kb][(wn * 32 + (cb) * 16 + frow) * 32 + fkp]; \
  } while (0)

#define MFMA12(cb)                                                               \
  do {                                                                           \
    __builtin_amdgcn_s_setprio(1);                                               \
    _Pragma("unroll")                                                            \
    for (int g = 0; g < 3; ++g)                                                  \
      _Pragma("unroll")                                                          \
      for (int rb = 0; rb < 4; ++rb)                                             \
        acc[g][rb][cb] = __builtin_amdgcn_mfma_f32_16x16x32_bf16(                \
            af[rb], wf[g], acc[g][rb][cb], 0, 0, 0);                             \
    __builtin_amdgcn_s_setprio(0);                                               \
  } while (0)

// 4 phases per K-tile; all next-tile loads issue in phase 0; vmcnt(0) only at
// the tile's final phase (before its closing barrier).
#define GEMM_PASS(APTR, WPTR, LD, KTOT)                                          \
  do {                                                                           \
    STAGE_TILE(APTR, WPTR, LD, 0, 0);                                            \
    WAITVM0;                                                                     \
    BAR;                                                                         \
    const int NT = (KTOT) / 64;                                                  \
    for (int t = 0; t < NT; ++t) {                                               \
      const int bb = t & 1;                                                      \
      /* phase 0: af(kb0) + wf(kb0,cb0) + prefetch t+1 */                        \
      READ_AF(bb, 0);                                                            \
      READ_WF(bb, 0, 0);                                                         \
      if (t + 1 < NT) STAGE_TILE(APTR, WPTR, LD, bb ^ 1, (t + 1) * 64);          \
      BAR; LGKM0;                                                                \
      MFMA12(0);                                                                 \
      BAR;                                                                       \
      /* phase 1: wf(kb0,cb1) */                                                 \
      READ_WF(bb, 0, 1);                                                         \
      BAR; LGKM0;                                                                \
      MFMA12(1);                                                                 \
      BAR;                                                                       \
      /* phase 2: af(kb1) + wf(kb1,cb0) */                                       \
      READ_AF(bb, 1);                                                            \
      READ_WF(bb, 1, 0);                                                         \
      BAR; LGKM0;                                                                \
      MFMA12(0);                                                                 \
      BAR;                                                                       \
      /* phase 3: wf(kb1,cb1); drain prefetch before buffer swap */              \
      READ_WF(bb, 1, 1);                                                         \
      BAR; LGKM0;                                                                \
      MFMA12(1);                                                                 \
      WAITVM0;                                                                   \
      BAR;                                                                       \
    }                                                                            \
  } while (0)

  // ---- K-loop 1: x @ Wih^T (K = 512) ----
  GEMM_PASS(xb, wihb, I_N, I_N);

  // park ih gates as packed bf16, re-zero accs (register-only, between passes)
#pragma unroll
  for (int g = 0; g < 3; ++g)
#pragma unroll
    for (int rb = 0; rb < 4; ++rb)
#pragma unroll
      for (int cb = 0; cb < 2; ++cb) {
        park[g][rb][cb][0] = pack2bf(acc[g][rb][cb][0], acc[g][rb][cb][1]);
        park[g][rb][cb][1] = pack2bf(acc[g][rb][cb][2], acc[g][rb][cb][3]);
#pragma unroll
        for (int r = 0; r < 4; ++r) acc[g][rb][cb][r] = 0.0f;
      }

  // ---- K-loop 2: hdec @ Whh^T (K = 1024) ----
  GEMM_PASS(hdec, whhb, H_N, H_N);

#undef GEMM_PASS
#undef MFMA12
#undef READ_WF
#undef READ_AF
#undef STAGE_TILE

  // ---- epilogue: gates + output ----
  // C/D 16x16: col = lane&15, row = (lane>>4)*4 + reg
#pragma unroll
  for (int cb = 0; cb < 2; ++cb) {
    const int col = j0 + wn * 32 + cb * 16 + frow;
    const float b_ir = bih[col];
    const float b_iz = bih[H_N + col];
    const float b_in = bih[2 * H_N + col];
    const float b_hr = bhh[col];
    const float b_hz = bhh[H_N + col];
    const float b_hn = bhh[2 * H_N + col];
#pragma unroll
    for (int rb = 0; rb < 4; ++rb) {
      const int rbase = m0 + wm * 64 + rb * 16 + (lane >> 4) * 4;
#pragma unroll
      for (int r = 0; r < 4; ++r) {
        const int row = rbase + r;
        const int sh = (r & 1) * 16;
        float ir  = bf2f((u16)(park[0][rb][cb][r >> 1] >> sh)) + b_ir;
        float iz  = bf2f((u16)(park[1][rb][cb][r >> 1] >> sh)) + b_iz;
        float in_ = bf2f((u16)(park[2][rb][cb][r >> 1] >> sh)) + b_in;
        float hr = acc[0][rb][cb][r] + b_hr;
        float hz = acc[1][rb][cb][r] + b_hz;
        float hn = acc[2][rb][cb][r] + b_hn;
        float rg = 1.0f / (1.0f + __expf(-(ir + hr)));
        float zg = 1.0f / (1.0f + __expf(-(iz + hz)));
        float s  = in_ + rg * hn;
        float e  = __expf(2.0f * s);
        float ng = (e - 1.0f) / (e + 1.0f);   // tanh(s), stable both tails
        float hv = bf2f(hdec[(size_t)row * H_N + col]);
        out[(size_t)row * H_N + col] = ng + zg * (hv - ng);
      }
    }
  }
}

extern "C" void kernel_launch(void* const* d_in, const int* in_sizes, int n_in,
                              void* d_out, int out_size, void* d_ws, size_t ws_size,
                              hipStream_t stream) {
  const float* x     = (const float*)d_in[0];
  const float* delta = (const float*)d_in[1];
  const float* h     = (const float*)d_in[2];
  const float* wih   = (const float*)d_in[3];
  const float* whh   = (const float*)d_in[4];
  const float* bih   = (const float*)d_in[5];
  const float* bhh   = (const float*)d_in[6];
  const float* wg    = (const float*)d_in[7];
  const float* bg    = (const float*)d_in[8];
  float* out = (float*)d_out;

  char* ws = (char*)d_ws;
  u16* xb   = (u16*)(ws);                 // x bf16:   8192*512*2  =  8,388,608 B
  u16* hdec = (u16*)(ws + 8388608);       // hdec bf16:8192*1024*2 = 16,777,216 B
  u16* wihb = (u16*)(ws + 25165824);      // Wih bf16: 3072*512*2  =  3,145,728 B
  u16* whhb = (u16*)(ws + 28311552);      // Whh bf16: 3072*1024*2 =  6,291,456 B

  prep<<<8448, 256, 0, stream>>>(x, wih, whh, h, delta, wg, bg, xb, wihb, whhb, hdec);
  gru_gemm<<<dim3(B_N / 256, H_N / 64), 512, 0, stream>>>(xb, hdec, wihb, whhb, bih, bhh, out);
}

// Round 4
// 272.123 us; speedup vs baseline: 1.0545x; 1.0545x over previous
//
#include <hip/hip_runtime.h>
#include <hip/hip_bf16.h>
#include <stdint.h>

// Problem constants (B=8192, I=512, H=1024, D=8)
#define B_N 8192
#define I_N 512
#define H_N 1024

typedef __bf16 bf16x8 __attribute__((ext_vector_type(8)));
typedef float f32x4 __attribute__((ext_vector_type(4)));
typedef unsigned short u16;
typedef unsigned int u32;

__device__ inline void gld_lds16(const void* g, void* l) {
  __builtin_amdgcn_global_load_lds(
      (const __attribute__((address_space(1))) unsigned int*)g,
      (__attribute__((address_space(3))) unsigned int*)l,
      16, 0, 0);
}

__device__ inline u16 f2bf(float f) {
  __hip_bfloat16 h = __float2bfloat16(f);
  return __builtin_bit_cast(u16, h);
}

__device__ inline float bf2f(u16 b) {
  unsigned int u = ((unsigned int)b) << 16;
  return __builtin_bit_cast(float, u);
}

__device__ inline u32 pack2bf(float lo, float hi) {
  return (u32)f2bf(lo) | ((u32)f2bf(hi) << 16);
}

// ---------------- prep: fused bf16 conversion (x, Wih, Whh) + hidden decay ----
__global__ void prep(const float* __restrict__ x, const float* __restrict__ wih,
                     const float* __restrict__ whh, const float* __restrict__ h,
                     const float* __restrict__ delta, const float* __restrict__ wg,
                     const float* __restrict__ bg, u16* __restrict__ xb,
                     u16* __restrict__ wihb, u16* __restrict__ whhb,
                     u16* __restrict__ hdec) {
  const int b = blockIdx.x;
  if (b < 4352) {
    const float* src; u16* dst; int base;
    if (b < 2048)      { src = x;   dst = xb;   base = b; }
    else if (b < 2816) { src = wih; dst = wihb; base = b - 2048; }
    else               { src = whh; dst = whhb; base = b - 2816; }
    const int i = (base * 256 + (int)threadIdx.x) * 8;
    float4 a0 = *(const float4*)(src + i);
    float4 a1 = *(const float4*)(src + i + 4);
    union { u16 u[8]; float4 v; } pk;
    pk.u[0] = f2bf(a0.x); pk.u[1] = f2bf(a0.y); pk.u[2] = f2bf(a0.z); pk.u[3] = f2bf(a0.w);
    pk.u[4] = f2bf(a1.x); pk.u[5] = f2bf(a1.y); pk.u[6] = f2bf(a1.z); pk.u[7] = f2bf(a1.w);
    *(float4*)(dst + i) = pk.v;
  } else {
    const int idx8 = (b - 4352) * 2048 + (int)threadIdx.x * 8;  // over B*H, 8-aligned
    const int bb = idx8 >> 10;   // H_N = 1024
    const int j  = idx8 & 1023;
    const float4* d4 = (const float4*)(delta + (size_t)bb * 8);
    const float4 d0 = d4[0], d1 = d4[1];
    const float4* h4 = (const float4*)(h + idx8);
    const float4 h0 = h4[0], h1 = h4[1];
    const float4* b4 = (const float4*)(bg + j);
    const float4 bg0 = b4[0], bg1 = b4[1];
    const float hv[8]  = {h0.x, h0.y, h0.z, h0.w, h1.x, h1.y, h1.z, h1.w};
    const float bgv[8] = {bg0.x, bg0.y, bg0.z, bg0.w, bg1.x, bg1.y, bg1.z, bg1.w};
    union { u16 u[8]; float4 v; } pk;
#pragma unroll
    for (int t = 0; t < 8; ++t) {
      const float4* w4 = (const float4*)(wg + (size_t)(j + t) * 8);
      const float4 w0 = w4[0], w1 = w4[1];
      float s = d0.x*w0.x + d0.y*w0.y + d0.z*w0.z + d0.w*w0.w
              + d1.x*w1.x + d1.y*w1.y + d1.z*w1.z + d1.w*w1.w + bgv[t];
      s = s > 0.0f ? s : 0.0f;
      pk.u[t] = f2bf(__expf(-s) * hv[t]);
    }
    *(float4*)(hdec + idx8) = pk.v;
  }
}

// ---------- fused GRU GEMM — R0 structure + T3 minimum-2-phase pipeline ----------
// EXACT R0 geometry: 256 threads / 4 waves, block tile 128 rows x 64 cols x 3
// gates, BK=64 (2 kb of 32), wave tile 64x32, MFMA 16x16x32, XOR chunk swizzle
// (verified conflict-free), same staging & fragment addressing, same epilogue.
// ONLY change from R0 (102 us, MfmaUtil 31%): double-buffered LDS + prefetch
// distance 1 with ONE barrier per K-step (R0 had two):
//   loop t: STAGE(buf[t^1], tile t+1)  -> compute buf[t&1] -> vmcnt(0) -> s_barrier
// The vmcnt(0) drain is covered by the full compute phase (48 MFMA + 20
// ds_read issued since the loads) instead of sitting raw at the barrier.
// Safety of the single barrier: every ds_read of buf[cur] is consumed by an
// MFMA before the barrier (compiler lgkmcnt), so its LDS reads are complete
// when the next iteration's STAGE overwrites buf[cur]; vmcnt(0) before the
// barrier guarantees buf[cur^1] is fully written before any wave reads it.
// No setprio (T5 measured null-to-negative on 2-phase schedules).
// MFMA accumulation order over K identical to R0 -> bit-identical output.

#define BAR do { asm volatile("" ::: "memory"); __builtin_amdgcn_s_barrier(); \
                 asm volatile("" ::: "memory"); } while (0)
#define WAITVM0 asm volatile("s_waitcnt vmcnt(0)" ::: "memory")

__global__ __launch_bounds__(256, 2) void gru_gemm(
    const u16* __restrict__ xb,    // [B, I] bf16
    const u16* __restrict__ hdec,  // [B, H] bf16 (decayed h)
    const u16* __restrict__ wihb,  // [3H, I] bf16
    const u16* __restrict__ whhb,  // [3H, H] bf16
    const float* __restrict__ bih, // [3H]
    const float* __restrict__ bhh, // [3H]
    float* __restrict__ out)       // [B, H] f32
{
  // [buf][kb][row*32 + k]: A 32 KB + W 48 KB = 80 KB -> 2 blocks/CU
  __shared__ __attribute__((aligned(16))) u16 As[2][2][128 * 32];
  __shared__ __attribute__((aligned(16))) u16 Ws[2][3][2][64 * 32];

  const int tid  = threadIdx.x;
  const int lane = tid & 63;
  const int wave = tid >> 6;
  const int wm = wave & 1;   // row half (64 rows each)
  const int wn = wave >> 1;  // col half (32 cols each)
  const int m0 = blockIdx.x * 128;
  const int j0 = blockIdx.y * 64;

  const int srow = tid >> 2;                                // 0..63 staging row
  const int sk   = (((tid & 3) ^ ((tid >> 3) & 3)) * 8);    // swizzled global chunk
  const int frow = lane & 15;                               // fragment row/col
  const int fkp  = (((lane >> 4) ^ ((frow >> 1) & 3)) * 8); // swizzled read offset

  f32x4 acc[3][4][2];
  u32 park[3][4][2][2];

#pragma unroll
  for (int g = 0; g < 3; ++g)
#pragma unroll
    for (int rb = 0; rb < 4; ++rb)
#pragma unroll
      for (int cb = 0; cb < 2; ++cb)
#pragma unroll
        for (int r = 0; r < 4; ++r) acc[g][rb][cb][r] = 0.0f;

// 10 loads: one full K-tile (2 kb x (2 A-halves + 3 gate W tiles))
#define STAGE_TILE(APTR, WPTR, LD, bb, kk)                                      \
  do {                                                                          \
    _Pragma("unroll")                                                           \
    for (int kb = 0; kb < 2; ++kb) {                                            \
      _Pragma("unroll")                                                         \
      for (int o = 0; o < 2; ++o)                                               \
        gld_lds16((APTR) + (size_t)(m0 + o * 64 + srow) * (LD) + (kk) + kb * 32 + sk, \
                  &As[bb][kb][o * 2048 + tid * 8]);                             \
      _Pragma("unroll")                                                         \
      for (int g = 0; g < 3; ++g)                                               \
        gld_lds16((WPTR) + (size_t)(g * H_N + j0 + srow) * (LD) + (kk) + kb * 32 + sk, \
                  &Ws[bb][g][kb][tid * 8]);                                     \
    }                                                                           \
  } while (0)

// one K-tile of compute: 20 ds_read_b128 + 48 MFMA (identical to R0 body)
#define COMPUTE_TILE(bb)                                                        \
  do {                                                                          \
    _Pragma("unroll")                                                           \
    for (int kb = 0; kb < 2; ++kb) {                                            \
      bf16x8 af[4];                                                             \
      _Pragma("unroll")                                                         \
      for (int rb = 0; rb < 4; ++rb)                                            \
        af[rb] = *(const bf16x8*)&As[bb][kb][(wm * 64 + rb * 16 + frow) * 32 + fkp]; \
      _Pragma("unroll")                                                         \
      for (int g = 0; g < 3; ++g) {                                             \
        _Pragma("unroll")                                                       \
        for (int cb = 0; cb < 2; ++cb) {                                        \
          bf16x8 wf = *(const bf16x8*)&Ws[bb][g][kb][(wn * 32 + cb * 16 + frow) * 32 + fkp]; \
          _Pragma("unroll")                                                     \
          for (int rb = 0; rb < 4; ++rb)                                        \
            acc[g][rb][cb] = __builtin_amdgcn_mfma_f32_16x16x32_bf16(           \
                af[rb], wf, acc[g][rb][cb], 0, 0, 0);                           \
        }                                                                       \
      }                                                                         \
    }                                                                           \
  } while (0)

#define GEMM_PASS(APTR, WPTR, LD, KTOT)                                         \
  do {                                                                          \
    STAGE_TILE(APTR, WPTR, LD, 0, 0);                                           \
    WAITVM0;                                                                    \
    BAR;                                                                        \
    const int NT = (KTOT) / 64;                                                 \
    for (int t = 0; t < NT; ++t) {                                              \
      const int bb = t & 1;                                                     \
      if (t + 1 < NT) STAGE_TILE(APTR, WPTR, LD, bb ^ 1, (t + 1) * 64);         \
      COMPUTE_TILE(bb);                                                         \
      WAITVM0;                                                                  \
      BAR;                                                                      \
    }                                                                           \
  } while (0)

  // ---- K-loop 1: x @ Wih^T (K = 512) ----
  GEMM_PASS(xb, wihb, I_N, I_N);

  // park ih gates as packed bf16, re-zero accs (register-only, between passes)
#pragma unroll
  for (int g = 0; g < 3; ++g)
#pragma unroll
    for (int rb = 0; rb < 4; ++rb)
#pragma unroll
      for (int cb = 0; cb < 2; ++cb) {
        park[g][rb][cb][0] = pack2bf(acc[g][rb][cb][0], acc[g][rb][cb][1]);
        park[g][rb][cb][1] = pack2bf(acc[g][rb][cb][2], acc[g][rb][cb][3]);
#pragma unroll
        for (int r = 0; r < 4; ++r) acc[g][rb][cb][r] = 0.0f;
      }

  // ---- K-loop 2: hdec @ Whh^T (K = 1024) ----
  GEMM_PASS(hdec, whhb, H_N, H_N);

#undef GEMM_PASS
#undef COMPUTE_TILE
#undef STAGE_TILE

  // ---- epilogue: gates + output ----
  // C/D 16x16: col = lane&15, row = (lane>>4)*4 + reg
#pragma unroll
  for (int cb = 0; cb < 2; ++cb) {
    const int col = j0 + wn * 32 + cb * 16 + frow;
    const float b_ir = bih[col];
    const float b_iz = bih[H_N + col];
    const float b_in = bih[2 * H_N + col];
    const float b_hr = bhh[col];
    const float b_hz = bhh[H_N + col];
    const float b_hn = bhh[2 * H_N + col];
#pragma unroll
    for (int rb = 0; rb < 4; ++rb) {
      const int rbase = m0 + wm * 64 + rb * 16 + (lane >> 4) * 4;
#pragma unroll
      for (int r = 0; r < 4; ++r) {
        const int row = rbase + r;
        const int sh = (r & 1) * 16;
        float ir  = bf2f((u16)(park[0][rb][cb][r >> 1] >> sh)) + b_ir;
        float iz  = bf2f((u16)(park[1][rb][cb][r >> 1] >> sh)) + b_iz;
        float in_ = bf2f((u16)(park[2][rb][cb][r >> 1] >> sh)) + b_in;
        float hr = acc[0][rb][cb][r] + b_hr;
        float hz = acc[1][rb][cb][r] + b_hz;
        float hn = acc[2][rb][cb][r] + b_hn;
        float rg = 1.0f / (1.0f + __expf(-(ir + hr)));
        float zg = 1.0f / (1.0f + __expf(-(iz + hz)));
        float s  = in_ + rg * hn;
        float e  = __expf(2.0f * s);
        float ng = (e - 1.0f) / (e + 1.0f);   // tanh(s), stable both tails
        float hv = bf2f(hdec[(size_t)row * H_N + col]);
        out[(size_t)row * H_N + col] = ng + zg * (hv - ng);
      }
    }
  }
}

extern "C" void kernel_launch(void* const* d_in, const int* in_sizes, int n_in,
                              void* d_out, int out_size, void* d_ws, size_t ws_size,
                              hipStream_t stream) {
  const float* x     = (const float*)d_in[0];
  const float* delta = (const float*)d_in[1];
  const float* h     = (const float*)d_in[2];
  const float* wih   = (const float*)d_in[3];
  const float* whh   = (const float*)d_in[4];
  const float* bih   = (const float*)d_in[5];
  const float* bhh   = (const float*)d_in[6];
  const float* wg    = (const float*)d_in[7];
  const float* bg    = (const float*)d_in[8];
  float* out = (float*)d_out;

  char* ws = (char*)d_ws;
  u16* xb   = (u16*)(ws);                 // x bf16:   8192*512*2  =  8,388,608 B
  u16* hdec = (u16*)(ws + 8388608);       // hdec bf16:8192*1024*2 = 16,777,216 B
  u16* wihb = (u16*)(ws + 25165824);      // Wih bf16: 3072*512*2  =  3,145,728 B
  u16* whhb = (u16*)(ws + 28311552);      // Whh bf16: 3072*1024*2 =  6,291,456 B

  prep<<<8448, 256, 0, stream>>>(x, wih, whh, h, delta, wg, bg, xb, wihb, whhb, hdec);
  gru_gemm<<<dim3(B_N / 128, H_N / 64), 256, 0, stream>>>(xb, hdec, wihb, whhb, bih, bhh, out);
}

// Round 6
// 263.675 us; speedup vs baseline: 1.0883x; 1.0320x over previous
//
#include <hip/hip_runtime.h>
#include <hip/hip_bf16.h>
#include <stdint.h>

// Problem constants (B=8192, I=512, H=1024, D=8)
#define B_N 8192
#define I_N 512
#define H_N 1024

typedef __bf16 bf16x8 __attribute__((ext_vector_type(8)));
typedef float f32x4 __attribute__((ext_vector_type(4)));
typedef unsigned short u16;
typedef unsigned int u32;

__device__ inline void gld_lds16(const void* g, void* l) {
  __builtin_amdgcn_global_load_lds(
      (const __attribute__((address_space(1))) unsigned int*)g,
      (__attribute__((address_space(3))) unsigned int*)l,
      16, 0, 0);
}

__device__ inline u16 f2bf(float f) {
  __hip_bfloat16 h = __float2bfloat16(f);
  return __builtin_bit_cast(u16, h);
}

__device__ inline float bf2f(u16 b) {
  unsigned int u = ((unsigned int)b) << 16;
  return __builtin_bit_cast(float, u);
}

__device__ inline u32 pack2bf(float lo, float hi) {
  return (u32)f2bf(lo) | ((u32)f2bf(hi) << 16);
}

// ---------------- prep: fused bf16 conversion (x, Wih, Whh) + hidden decay ----
__global__ void prep(const float* __restrict__ x, const float* __restrict__ wih,
                     const float* __restrict__ whh, const float* __restrict__ h,
                     const float* __restrict__ delta, const float* __restrict__ wg,
                     const float* __restrict__ bg, u16* __restrict__ xb,
                     u16* __restrict__ wihb, u16* __restrict__ whhb,
                     u16* __restrict__ hdec) {
  const int b = blockIdx.x;
  if (b < 4352) {
    const float* src; u16* dst; int base;
    if (b < 2048)      { src = x;   dst = xb;   base = b; }
    else if (b < 2816) { src = wih; dst = wihb; base = b - 2048; }
    else               { src = whh; dst = whhb; base = b - 2816; }
    const int i = (base * 256 + (int)threadIdx.x) * 8;
    float4 a0 = *(const float4*)(src + i);
    float4 a1 = *(const float4*)(src + i + 4);
    union { u16 u[8]; float4 v; } pk;
    pk.u[0] = f2bf(a0.x); pk.u[1] = f2bf(a0.y); pk.u[2] = f2bf(a0.z); pk.u[3] = f2bf(a0.w);
    pk.u[4] = f2bf(a1.x); pk.u[5] = f2bf(a1.y); pk.u[6] = f2bf(a1.z); pk.u[7] = f2bf(a1.w);
    *(float4*)(dst + i) = pk.v;
  } else {
    const int idx8 = (b - 4352) * 2048 + (int)threadIdx.x * 8;  // over B*H, 8-aligned
    const int bb = idx8 >> 10;   // H_N = 1024
    const int j  = idx8 & 1023;
    const float4* d4 = (const float4*)(delta + (size_t)bb * 8);
    const float4 d0 = d4[0], d1 = d4[1];
    const float4* h4 = (const float4*)(h + idx8);
    const float4 h0 = h4[0], h1 = h4[1];
    const float4* b4 = (const float4*)(bg + j);
    const float4 bg0 = b4[0], bg1 = b4[1];
    const float hv[8]  = {h0.x, h0.y, h0.z, h0.w, h1.x, h1.y, h1.z, h1.w};
    const float bgv[8] = {bg0.x, bg0.y, bg0.z, bg0.w, bg1.x, bg1.y, bg1.z, bg1.w};
    union { u16 u[8]; float4 v; } pk;
#pragma unroll
    for (int t = 0; t < 8; ++t) {
      const float4* w4 = (const float4*)(wg + (size_t)(j + t) * 8);
      const float4 w0 = w4[0], w1 = w4[1];
      float s = d0.x*w0.x + d0.y*w0.y + d0.z*w0.z + d0.w*w0.w
              + d1.x*w1.x + d1.y*w1.y + d1.z*w1.z + d1.w*w1.w + bgv[t];
      s = s > 0.0f ? s : 0.0f;
      pk.u[t] = f2bf(__expf(-s) * hv[t]);
    }
    *(float4*)(hdec + idx8) = pk.v;
  }
}

// ---------- fused GRU GEMM — EXACT R0 structure + XCD-chunked block swizzle ----
// Body is byte-for-byte the verified 102-us R0 kernel (single-buffer 40 KB LDS,
// two __syncthreads per K-step, compiler-scheduled waits). ONLY change: block
// index mapping (T1). Hand-pipelined variants (R2/R3/R4) all regressed —
// 2-blocks/CU co-residency already overlaps the drain; restructuring only
// added barrier overhead or L2 thrash (R4: FETCH 70->99 MB).
//
// Swizzle mechanism: HW dispatches block id round-robin across 8 XCDs
// (id % 8 = XCD). Map id -> (m0, j0) so each XCD owns 2 j0-columns x all 64
// row-tiles: per-XCD W working set = 2 * 590 KB = 1.18 MB (fits 4 MB L2,
// was 9.4 MB touched by every XCD), A re-reads absorbed by the 256 MB LLC.
// Bijective: 1024 blocks = 8 xcd * 2 col * 64 row exactly.
//   xcd = id & 7; w = id >> 3; m0 = (w & 63)*128; j0 = (xcd*2 + (w >> 6))*64
__global__ __launch_bounds__(256, 2) void gru_gemm(
    const u16* __restrict__ xb,    // [B, I] bf16
    const u16* __restrict__ hdec,  // [B, H] bf16 (decayed h)
    const u16* __restrict__ wihb,  // [3H, I] bf16
    const u16* __restrict__ whhb,  // [3H, H] bf16
    const float* __restrict__ bih, // [3H]
    const float* __restrict__ bhh, // [3H]
    float* __restrict__ out)       // [B, H] f32
{
  __shared__ __attribute__((aligned(16))) u16 As[2][128 * 32];     // 16 KB
  __shared__ __attribute__((aligned(16))) u16 Ws[3][2][64 * 32];   // 24 KB

  const int tid  = threadIdx.x;
  const int lane = tid & 63;
  const int wave = tid >> 6;
  const int wm = wave & 1;   // row half (64 rows each)
  const int wn = wave >> 1;  // col half (32 cols each)

  // XCD-chunked swizzle (see header comment)
  const int id  = blockIdx.x;
  const int xcd = id & 7;
  const int w   = id >> 3;
  const int m0  = (w & 63) * 128;
  const int j0  = (xcd * 2 + (w >> 6)) * 64;

  const int srow = tid >> 2;                              // 0..63 staging row
  const int sk   = (((tid & 3) ^ ((tid >> 3) & 3)) * 8);  // swizzled global chunk
  const int frow = lane & 15;                             // fragment row/col
  const int fkp  = (((lane >> 4) ^ ((frow >> 1) & 3)) * 8); // swizzled read offset

  f32x4 acc[3][4][2];
  u32 park[3][4][2][2];

#pragma unroll
  for (int g = 0; g < 3; ++g)
#pragma unroll
    for (int rb = 0; rb < 4; ++rb)
#pragma unroll
      for (int cb = 0; cb < 2; ++cb)
#pragma unroll
        for (int r = 0; r < 4; ++r) acc[g][rb][cb][r] = 0.0f;

#define GEMM_PASS(APTR, WPTR, LD, KTOT)                                         \
  for (int k0 = 0; k0 < (KTOT); k0 += 64) {                                     \
    _Pragma("unroll")                                                           \
    for (int kb = 0; kb < 2; ++kb) {                                            \
      _Pragma("unroll")                                                         \
      for (int o = 0; o < 2; ++o)                                               \
        gld_lds16((APTR) + (size_t)(m0 + o * 64 + srow) * (LD) + k0 + kb * 32 + sk, \
                  &As[kb][o * 2048 + tid * 8]);                                 \
      _Pragma("unroll")                                                         \
      for (int g = 0; g < 3; ++g)                                               \
        gld_lds16((WPTR) + (size_t)(g * H_N + j0 + srow) * (LD) + k0 + kb * 32 + sk, \
                  &Ws[g][kb][tid * 8]);                                         \
    }                                                                           \
    __syncthreads();                                                            \
    _Pragma("unroll")                                                           \
    for (int kb = 0; kb < 2; ++kb) {                                            \
      bf16x8 af[4];                                                             \
      _Pragma("unroll")                                                         \
      for (int rb = 0; rb < 4; ++rb)                                            \
        af[rb] = *(const bf16x8*)&As[kb][(wm * 64 + rb * 16 + frow) * 32 + fkp]; \
      _Pragma("unroll")                                                         \
      for (int g = 0; g < 3; ++g) {                                             \
        _Pragma("unroll")                                                       \
        for (int cb = 0; cb < 2; ++cb) {                                        \
          bf16x8 wf = *(const bf16x8*)&Ws[g][kb][(wn * 32 + cb * 16 + frow) * 32 + fkp]; \
          _Pragma("unroll")                                                     \
          for (int rb = 0; rb < 4; ++rb)                                        \
            acc[g][rb][cb] = __builtin_amdgcn_mfma_f32_16x16x32_bf16(           \
                af[rb], wf, acc[g][rb][cb], 0, 0, 0);                           \
        }                                                                       \
      }                                                                         \
    }                                                                           \
    __syncthreads();                                                            \
  }

  // ---- K-loop 1: x @ Wih^T (K = 512) ----
  GEMM_PASS(xb, wihb, I_N, I_N)

  // park ih gates as packed bf16, re-zero accs
#pragma unroll
  for (int g = 0; g < 3; ++g)
#pragma unroll
    for (int rb = 0; rb < 4; ++rb)
#pragma unroll
      for (int cb = 0; cb < 2; ++cb) {
        park[g][rb][cb][0] = pack2bf(acc[g][rb][cb][0], acc[g][rb][cb][1]);
        park[g][rb][cb][1] = pack2bf(acc[g][rb][cb][2], acc[g][rb][cb][3]);
#pragma unroll
        for (int r = 0; r < 4; ++r) acc[g][rb][cb][r] = 0.0f;
      }

  // ---- K-loop 2: hdec @ Whh^T (K = 1024) ----
  GEMM_PASS(hdec, whhb, H_N, H_N)

#undef GEMM_PASS

  // ---- epilogue: gates + output ----
  // C/D 16x16: col = lane&15, row = (lane>>4)*4 + reg
#pragma unroll
  for (int cb = 0; cb < 2; ++cb) {
    const int col = j0 + wn * 32 + cb * 16 + frow;
    const float b_ir = bih[col];
    const float b_iz = bih[H_N + col];
    const float b_in = bih[2 * H_N + col];
    const float b_hr = bhh[col];
    const float b_hz = bhh[H_N + col];
    const float b_hn = bhh[2 * H_N + col];
#pragma unroll
    for (int rb = 0; rb < 4; ++rb) {
      const int rbase = m0 + wm * 64 + rb * 16 + (lane >> 4) * 4;
#pragma unroll
      for (int r = 0; r < 4; ++r) {
        const int row = rbase + r;
        const int sh = (r & 1) * 16;
        float ir  = bf2f((u16)(park[0][rb][cb][r >> 1] >> sh)) + b_ir;
        float iz  = bf2f((u16)(park[1][rb][cb][r >> 1] >> sh)) + b_iz;
        float in_ = bf2f((u16)(park[2][rb][cb][r >> 1] >> sh)) + b_in;
        float hr = acc[0][rb][cb][r] + b_hr;
        float hz = acc[1][rb][cb][r] + b_hz;
        float hn = acc[2][rb][cb][r] + b_hn;
        float rg = 1.0f / (1.0f + __expf(-(ir + hr)));
        float zg = 1.0f / (1.0f + __expf(-(iz + hz)));
        float s  = in_ + rg * hn;
        float e  = __expf(2.0f * s);
        float ng = (e - 1.0f) / (e + 1.0f);   // tanh(s), stable both tails
        float hv = bf2f(hdec[(size_t)row * H_N + col]);
        out[(size_t)row * H_N + col] = ng + zg * (hv - ng);
      }
    }
  }
}

extern "C" void kernel_launch(void* const* d_in, const int* in_sizes, int n_in,
                              void* d_out, int out_size, void* d_ws, size_t ws_size,
                              hipStream_t stream) {
  const float* x     = (const float*)d_in[0];
  const float* delta = (const float*)d_in[1];
  const float* h     = (const float*)d_in[2];
  const float* wih   = (const float*)d_in[3];
  const float* whh   = (const float*)d_in[4];
  const float* bih   = (const float*)d_in[5];
  const float* bhh   = (const float*)d_in[6];
  const float* wg    = (const float*)d_in[7];
  const float* bg    = (const float*)d_in[8];
  float* out = (float*)d_out;

  char* ws = (char*)d_ws;
  u16* xb   = (u16*)(ws);                 // x bf16:   8192*512*2  =  8,388,608 B
  u16* hdec = (u16*)(ws + 8388608);       // hdec bf16:8192*1024*2 = 16,777,216 B
  u16* wihb = (u16*)(ws + 25165824);      // Wih bf16: 3072*512*2  =  3,145,728 B
  u16* whhb = (u16*)(ws + 28311552);      // Whh bf16: 3072*1024*2 =  6,291,456 B

  prep<<<8448, 256, 0, stream>>>(x, wih, whh, h, delta, wg, bg, xb, wihb, whhb, hdec);
  gru_gemm<<<1024, 256, 0, stream>>>(xb, hdec, wihb, whhb, bih, bhh, out);
}

// Round 7
// 251.206 us; speedup vs baseline: 1.1423x; 1.0496x over previous
//
#include <hip/hip_runtime.h>
#include <hip/hip_bf16.h>
#include <stdint.h>

// Problem constants (B=8192, I=512, H=1024, D=8)
#define B_N 8192
#define I_N 512
#define H_N 1024

typedef __bf16 bf16x8 __attribute__((ext_vector_type(8)));
typedef float f32x4 __attribute__((ext_vector_type(4)));
typedef unsigned short u16;
typedef unsigned int u32;

__device__ inline void gld_lds16(const void* g, void* l) {
  __builtin_amdgcn_global_load_lds(
      (const __attribute__((address_space(1))) unsigned int*)g,
      (__attribute__((address_space(3))) unsigned int*)l,
      16, 0, 0);
}

__device__ inline u16 f2bf(float f) {
  __hip_bfloat16 h = __float2bfloat16(f);
  return __builtin_bit_cast(u16, h);
}

__device__ inline float bf2f(u16 b) {
  unsigned int u = ((unsigned int)b) << 16;
  return __builtin_bit_cast(float, u);
}

__device__ inline u32 pack2bf(float lo, float hi) {
  return (u32)f2bf(lo) | ((u32)f2bf(hi) << 16);
}

// ---------------- prep: fused bf16 conversion (x, Wih, Whh) + hidden decay ----
__global__ void prep(const float* __restrict__ x, const float* __restrict__ wih,
                     const float* __restrict__ whh, const float* __restrict__ h,
                     const float* __restrict__ delta, const float* __restrict__ wg,
                     const float* __restrict__ bg, u16* __restrict__ xb,
                     u16* __restrict__ wihb, u16* __restrict__ whhb,
                     u16* __restrict__ hdec) {
  const int b = blockIdx.x;
  if (b < 4352) {
    const float* src; u16* dst; int base;
    if (b < 2048)      { src = x;   dst = xb;   base = b; }
    else if (b < 2816) { src = wih; dst = wihb; base = b - 2048; }
    else               { src = whh; dst = whhb; base = b - 2816; }
    const int i = (base * 256 + (int)threadIdx.x) * 8;
    float4 a0 = *(const float4*)(src + i);
    float4 a1 = *(const float4*)(src + i + 4);
    union { u16 u[8]; float4 v; } pk;
    pk.u[0] = f2bf(a0.x); pk.u[1] = f2bf(a0.y); pk.u[2] = f2bf(a0.z); pk.u[3] = f2bf(a0.w);
    pk.u[4] = f2bf(a1.x); pk.u[5] = f2bf(a1.y); pk.u[6] = f2bf(a1.z); pk.u[7] = f2bf(a1.w);
    *(float4*)(dst + i) = pk.v;
  } else {
    const int idx8 = (b - 4352) * 2048 + (int)threadIdx.x * 8;  // over B*H, 8-aligned
    const int bb = idx8 >> 10;   // H_N = 1024
    const int j  = idx8 & 1023;
    const float4* d4 = (const float4*)(delta + (size_t)bb * 8);
    const float4 d0 = d4[0], d1 = d4[1];
    const float4* h4 = (const float4*)(h + idx8);
    const float4 h0 = h4[0], h1 = h4[1];
    const float4* b4 = (const float4*)(bg + j);
    const float4 bg0 = b4[0], bg1 = b4[1];
    const float hv[8]  = {h0.x, h0.y, h0.z, h0.w, h1.x, h1.y, h1.z, h1.w};
    const float bgv[8] = {bg0.x, bg0.y, bg0.z, bg0.w, bg1.x, bg1.y, bg1.z, bg1.w};
    union { u16 u[8]; float4 v; } pk;
#pragma unroll
    for (int t = 0; t < 8; ++t) {
      const float4* w4 = (const float4*)(wg + (size_t)(j + t) * 8);
      const float4 w0 = w4[0], w1 = w4[1];
      float s = d0.x*w0.x + d0.y*w0.y + d0.z*w0.z + d0.w*w0.w
              + d1.x*w1.x + d1.y*w1.y + d1.z*w1.z + d1.w*w1.w + bgv[t];
      s = s > 0.0f ? s : 0.0f;
      pk.u[t] = f2bf(__expf(-s) * hv[t]);
    }
    *(float4*)(hdec + idx8) = pk.v;
  }
}

// ---------- fused GRU GEMM — R0 structure, BK=128 (halved barrier-drain count) ----
// Body identical to the verified 102-us R0 kernel EXCEPT the K-step is 128
// instead of 64: single-buffer LDS grows 40->80 KB (still fits measured ~2
// blocks/CU residency), barrier count halves (12 K-steps vs 24), so the
// per-K-step vmcnt(0) drain at __syncthreads amortizes over 2x compute.
// Grid/swizzle reverted to R0's plain 2D mapping (R6's XCD remap tripled
// FETCH: dispatch->XCD assumption wrong on this machine).
// k processed in the same linear order (k0 + kb*32), so MFMA accumulation
// order is IDENTICAL to R0 -> bit-identical output (absmax 0.015625).
__global__ __launch_bounds__(256, 2) void gru_gemm(
    const u16* __restrict__ xb,    // [B, I] bf16
    const u16* __restrict__ hdec,  // [B, H] bf16 (decayed h)
    const u16* __restrict__ wihb,  // [3H, I] bf16
    const u16* __restrict__ whhb,  // [3H, H] bf16
    const float* __restrict__ bih, // [3H]
    const float* __restrict__ bhh, // [3H]
    float* __restrict__ out)       // [B, H] f32
{
  __shared__ __attribute__((aligned(16))) u16 As[4][128 * 32];     // 32 KB
  __shared__ __attribute__((aligned(16))) u16 Ws[3][4][64 * 32];   // 48 KB

  const int tid  = threadIdx.x;
  const int lane = tid & 63;
  const int wave = tid >> 6;
  const int wm = wave & 1;   // row half (64 rows each)
  const int wn = wave >> 1;  // col half (32 cols each)
  const int m0 = blockIdx.x * 128;
  const int j0 = blockIdx.y * 64;

  const int srow = tid >> 2;                              // 0..63 staging row
  const int sk   = (((tid & 3) ^ ((tid >> 3) & 3)) * 8);  // swizzled global chunk
  const int frow = lane & 15;                             // fragment row/col
  const int fkp  = (((lane >> 4) ^ ((frow >> 1) & 3)) * 8); // swizzled read offset

  f32x4 acc[3][4][2];
  u32 park[3][4][2][2];

#pragma unroll
  for (int g = 0; g < 3; ++g)
#pragma unroll
    for (int rb = 0; rb < 4; ++rb)
#pragma unroll
      for (int cb = 0; cb < 2; ++cb)
#pragma unroll
        for (int r = 0; r < 4; ++r) acc[g][rb][cb][r] = 0.0f;

#define GEMM_PASS(APTR, WPTR, LD, KTOT)                                         \
  for (int k0 = 0; k0 < (KTOT); k0 += 128) {                                    \
    _Pragma("unroll")                                                           \
    for (int kb = 0; kb < 4; ++kb) {                                            \
      _Pragma("unroll")                                                         \
      for (int o = 0; o < 2; ++o)                                               \
        gld_lds16((APTR) + (size_t)(m0 + o * 64 + srow) * (LD) + k0 + kb * 32 + sk, \
                  &As[kb][o * 2048 + tid * 8]);                                 \
      _Pragma("unroll")                                                         \
      for (int g = 0; g < 3; ++g)                                               \
        gld_lds16((WPTR) + (size_t)(g * H_N + j0 + srow) * (LD) + k0 + kb * 32 + sk, \
                  &Ws[g][kb][tid * 8]);                                         \
    }                                                                           \
    __syncthreads();                                                            \
    _Pragma("unroll")                                                           \
    for (int kb = 0; kb < 4; ++kb) {                                            \
      bf16x8 af[4];                                                             \
      _Pragma("unroll")                                                         \
      for (int rb = 0; rb < 4; ++rb)                                            \
        af[rb] = *(const bf16x8*)&As[kb][(wm * 64 + rb * 16 + frow) * 32 + fkp]; \
      _Pragma("unroll")                                                         \
      for (int g = 0; g < 3; ++g) {                                             \
        _Pragma("unroll")                                                       \
        for (int cb = 0; cb < 2; ++cb) {                                        \
          bf16x8 wf = *(const bf16x8*)&Ws[g][kb][(wn * 32 + cb * 16 + frow) * 32 + fkp]; \
          _Pragma("unroll")                                                     \
          for (int rb = 0; rb < 4; ++rb)                                        \
            acc[g][rb][cb] = __builtin_amdgcn_mfma_f32_16x16x32_bf16(           \
                af[rb], wf, acc[g][rb][cb], 0, 0, 0);                           \
        }                                                                       \
      }                                                                         \
    }                                                                           \
    __syncthreads();                                                            \
  }

  // ---- K-loop 1: x @ Wih^T (K = 512, 4 K-steps) ----
  GEMM_PASS(xb, wihb, I_N, I_N)

  // park ih gates as packed bf16, re-zero accs
#pragma unroll
  for (int g = 0; g < 3; ++g)
#pragma unroll
    for (int rb = 0; rb < 4; ++rb)
#pragma unroll
      for (int cb = 0; cb < 2; ++cb) {
        park[g][rb][cb][0] = pack2bf(acc[g][rb][cb][0], acc[g][rb][cb][1]);
        park[g][rb][cb][1] = pack2bf(acc[g][rb][cb][2], acc[g][rb][cb][3]);
#pragma unroll
        for (int r = 0; r < 4; ++r) acc[g][rb][cb][r] = 0.0f;
      }

  // ---- K-loop 2: hdec @ Whh^T (K = 1024, 8 K-steps) ----
  GEMM_PASS(hdec, whhb, H_N, H_N)

#undef GEMM_PASS

  // ---- epilogue: gates + output ----
  // C/D 16x16: col = lane&15, row = (lane>>4)*4 + reg
#pragma unroll
  for (int cb = 0; cb < 2; ++cb) {
    const int col = j0 + wn * 32 + cb * 16 + frow;
    const float b_ir = bih[col];
    const float b_iz = bih[H_N + col];
    const float b_in = bih[2 * H_N + col];
    const float b_hr = bhh[col];
    const float b_hz = bhh[H_N + col];
    const float b_hn = bhh[2 * H_N + col];
#pragma unroll
    for (int rb = 0; rb < 4; ++rb) {
      const int rbase = m0 + wm * 64 + rb * 16 + (lane >> 4) * 4;
#pragma unroll
      for (int r = 0; r < 4; ++r) {
        const int row = rbase + r;
        const int sh = (r & 1) * 16;
        float ir  = bf2f((u16)(park[0][rb][cb][r >> 1] >> sh)) + b_ir;
        float iz  = bf2f((u16)(park[1][rb][cb][r >> 1] >> sh)) + b_iz;
        float in_ = bf2f((u16)(park[2][rb][cb][r >> 1] >> sh)) + b_in;
        float hr = acc[0][rb][cb][r] + b_hr;
        float hz = acc[1][rb][cb][r] + b_hz;
        float hn = acc[2][rb][cb][r] + b_hn;
        float rg = 1.0f / (1.0f + __expf(-(ir + hr)));
        float zg = 1.0f / (1.0f + __expf(-(iz + hz)));
        float s  = in_ + rg * hn;
        float e  = __expf(2.0f * s);
        float ng = (e - 1.0f) / (e + 1.0f);   // tanh(s), stable both tails
        float hv = bf2f(hdec[(size_t)row * H_N + col]);
        out[(size_t)row * H_N + col] = ng + zg * (hv - ng);
      }
    }
  }
}

extern "C" void kernel_launch(void* const* d_in, const int* in_sizes, int n_in,
                              void* d_out, int out_size, void* d_ws, size_t ws_size,
                              hipStream_t stream) {
  const float* x     = (const float*)d_in[0];
  const float* delta = (const float*)d_in[1];
  const float* h     = (const float*)d_in[2];
  const float* wih   = (const float*)d_in[3];
  const float* whh   = (const float*)d_in[4];
  const float* bih   = (const float*)d_in[5];
  const float* bhh   = (const float*)d_in[6];
  const float* wg    = (const float*)d_in[7];
  const float* bg    = (const float*)d_in[8];
  float* out = (float*)d_out;

  char* ws = (char*)d_ws;
  u16* xb   = (u16*)(ws);                 // x bf16:   8192*512*2  =  8,388,608 B
  u16* hdec = (u16*)(ws + 8388608);       // hdec bf16:8192*1024*2 = 16,777,216 B
  u16* wihb = (u16*)(ws + 25165824);      // Wih bf16: 3072*512*2  =  3,145,728 B
  u16* whhb = (u16*)(ws + 28311552);      // Whh bf16: 3072*1024*2 =  6,291,456 B

  prep<<<8448, 256, 0, stream>>>(x, wih, whh, h, delta, wg, bg, xb, wihb, whhb, hdec);
  gru_gemm<<<dim3(B_N / 128, H_N / 64), 256, 0, stream>>>(xb, hdec, wihb, whhb, bih, bhh, out);
}